// Round 3
// baseline (123.396 us; speedup 1.0000x reference)
//
#include <hip/hip_runtime.h>
#include <math.h>

#define BB 32
#define SV 4096
#define SQ 1152
#define DD 128
#define FD 96
#define NS 32                      // chunks over SV
#define RPC (SV / NS)              // 128 rows per chunk
#define LOG2E 1.44269504088896340f

// ---- workspace layout (float offsets) ----
// G: [B,D,FD] group-of-12 sums of q        393216 floats
// P: [B,NS,6,D] partial v moments M1..M6   786432 floats
// li/A0/A0s:[B]  ip:[B,FD]
#define OFF_G    0
#define OFF_P    393216
#define OFF_LI   1183744
#define OFF_A0   1183776
#define OFF_A0S  1183808
#define OFF_IP   1183840

// Epoch fan-in counter: never reset; each replay targets the next multiple of 32.
__device__ unsigned g_cnt;

// K1 (fused): blocks [0,1024): v -> moment partials; blocks [1024,2560): q -> G.
__global__ __launch_bounds__(256) void k_pass1(const float* __restrict__ q,
                                               const float* __restrict__ v,
                                               float* __restrict__ ws) {
    __shared__ float red[6][8][DD];   // 24 KB (v-branch only)
    if (blockIdx.x < 1024) {
        int b = blockIdx.x >> 5, chunk = blockIdx.x & 31;
        int lane = threadIdx.x & 31, rowg = threadIdx.x >> 5;   // 8 rows in flight
        int d0 = lane * 4;
        const float* base = v + ((size_t)b * SV + (size_t)chunk * RPC) * DD;
        float s1[4] = {}, s2[4] = {}, s3[4] = {}, s4[4] = {}, s5[4] = {}, s6[4] = {};
        for (int i = 0; i < RPC / 8; i++) {
            float4 x = *reinterpret_cast<const float4*>(base + (size_t)(rowg + 8 * i) * DD + d0);
            float vv[4] = {x.x, x.y, x.z, x.w};
#pragma unroll
            for (int j = 0; j < 4; j++) {
                float a = vv[j], a2 = a * a, a4 = a2 * a2;
                s1[j] += a;       s2[j] += a2;      s3[j] += a2 * a;
                s4[j] += a4;      s5[j] += a4 * a;  s6[j] += a4 * a2;
            }
        }
#pragma unroll
        for (int j = 0; j < 4; j++) {
            red[0][rowg][d0 + j] = s1[j]; red[1][rowg][d0 + j] = s2[j];
            red[2][rowg][d0 + j] = s3[j]; red[3][rowg][d0 + j] = s4[j];
            red[4][rowg][d0 + j] = s5[j]; red[5][rowg][d0 + j] = s6[j];
        }
        __syncthreads();
        for (int t = threadIdx.x; t < 6 * DD; t += 256) {
            int m = t >> 7, d = t & (DD - 1);
            float a = 0;
#pragma unroll
            for (int r = 0; r < 8; r++) a += red[m][r][d];
            ws[OFF_P + ((size_t)(b * NS + chunk) * 6 + m) * DD + d] = a;
        }
    } else {
        int g = (blockIdx.x - 1024) * 256 + threadIdx.x;   // 0..393215
        const float4* p = reinterpret_cast<const float4*>(q + (size_t)g * 12);
        float4 a = p[0], b4 = p[1], c = p[2];
        ws[OFF_G + g] = ((a.x + a.y) + (a.z + a.w)) + ((b4.x + b4.y) + (b4.z + b4.w))
                      + ((c.x + c.y) + (c.z + c.w));
    }
}

// K2: per-batch finalize + 32-block fan-in + BatchNorm + output write.
// One block per b, 256 threads. Cross-block data: ip/A0/A0S/LI only (~13 KB).
// Fence cost is 32 blocks (round-1 measured 2560 fencing blocks ~= 130 us, so
// 32 ~= 1.6 us). All 32 blocks are co-resident on 256 CUs -> spin is safe.
__global__ __launch_bounds__(256) void k_finout(const float* __restrict__ v,
                                                const float* __restrict__ hmat,
                                                const float* __restrict__ hbias,
                                                const float* __restrict__ gamma,
                                                const float* __restrict__ beta,
                                                float* __restrict__ ws,
                                                float* __restrict__ out) {
    int b = blockIdx.x, tid = threadIdx.x;
    __shared__ float Gl[DD * 97];                 // padded: stride 96 would 32-way conflict
    __shared__ float qsl[DD], svl[DD], att0_sh[DD], ipl[FD];
    __shared__ float hm_l[3], hb_l[3];
    __shared__ float redc[10];
    __shared__ float sumq_sh, li_sh;
    __shared__ float bnA_sh[FD], bnB_sh[FD];
    const float* Gb = ws + OFF_G + (size_t)b * DD * FD;
#pragma unroll
    for (int i = 0; i < 12; i++) {                // stage G[b] (12288 floats) coalesced
        int idx = (i * 256 + tid) * 4;
        float4 x = *reinterpret_cast<const float4*>(Gb + idx);
        float xv[4] = {x.x, x.y, x.z, x.w};
#pragma unroll
        for (int j = 0; j < 4; j++) {
            int e = idx + j, dd = e / 96, f = e - dd * 96;
            Gl[dd * 97 + f] = xv[j];
        }
    }
    if (tid >= 128 && tid < 131) {
        int c = tid - 128;
        float h = 0;
        for (int x2 = 0; x2 < FD; x2++) h += hmat[c * FD + x2];
        hm_l[c] = h; hb_l[c] = hbias[c];
    }
    __syncthreads();
    float M1 = 0, M2 = 0, M3 = 0, M4 = 0, M5 = 0, M6 = 0;
    if (tid < 128) {                               // moments reduction (coalesced over d)
        const float* P = ws + OFF_P;
#pragma unroll 4
        for (int ch = 0; ch < NS; ch++) {
            const float* p = P + (size_t)(b * NS + ch) * 6 * DD + tid;
            M1 += p[0];      M2 += p[DD];     M3 += p[2 * DD];
            M4 += p[3 * DD]; M5 += p[4 * DD]; M6 += p[5 * DD];
        }
        svl[tid] = M1;
    } else {
        int d = tid - 128;                         // qs row sums from LDS (conflict-free)
        float qs = 0;
#pragma unroll 8
        for (int f = 0; f < FD; f++) qs += Gl[d * 97 + f];
        qsl[d] = qs;
    }
    __syncthreads();
    if (tid < 64) {                                // sumq: single-wave shuffle reduce
        float x = qsl[tid] + qsl[tid + 64];
#pragma unroll
        for (int ofs = 32; ofs; ofs >>= 1) x += __shfl_xor(x, ofs, 64);
        if (tid == 0) sumq_sh = x;
    }
    __syncthreads();
    if (tid < 128) {
        float sumq = sumq_sh;
        float v0 = v[((size_t)b * SV + 0) * DD + tid];
        float v1 = v[((size_t)b * SV + 1) * DD + tid];
        float v2 = v[((size_t)b * SV + 2) * DD + tid];
        float att0 = 0, att1 = 0, att2 = 0;
#pragma unroll
        for (int c = 0; c < 3; c++) {
            float alpha = hm_l[c] * sumq, hb = hb_l[c];
            float n2 = alpha * alpha * M2 + 2.f * alpha * hb * M1 + (float)SV * hb * hb;
            float tt = alpha / sqrtf(n2);          // |tt*v| <= ~0.1 -> Taylor-safe
            float Z = (float)SV + tt * (M1 + tt * (0.5f * M2 + tt * ((1.f / 6.f) * M3
                    + tt * ((1.f / 24.f) * M4 + tt * ((1.f / 120.f) * M5
                    + tt * (1.f / 720.f) * M6)))));
            float rz = 1.f / Z, tl = tt * LOG2E;
            att0 += exp2f(v0 * tl) * rz;
            att1 += exp2f(v1 * tl) * rz;
            att2 += exp2f(v2 * tl) * rz;
        }
        att0_sh[tid] = att0;
        float qsv = qsl[tid];
        float vals[5] = {att0, att0 * att0, att1 * qsv, att2 * qsv, M1};
#pragma unroll
        for (int i = 0; i < 5; i++) {
            float x = vals[i];
#pragma unroll
            for (int ofs = 32; ofs; ofs >>= 1) x += __shfl_xor(x, ofs, 64);
            if ((tid & 63) == 0) redc[(tid >> 6) * 5 + i] = x;
        }
    }
    __syncthreads();
    if (tid == 0) {
        float a0 = redc[0] + redc[5], a0s = redc[1] + redc[6];
        float r1 = redc[2] + redc[7], r2 = redc[3] + redc[8], vs = redc[4] + redc[9];
        ws[OFF_A0 + b] = a0; ws[OFF_A0S + b] = a0s;
        float li = vs * (r1 + r2);                 // l1 + l2
        ws[OFF_LI + b] = li; li_sh = li;
    }
    if (tid < FD) {                                // ip[b,f] GEMV from LDS
        float ip = 0;
#pragma unroll 8
        for (int k = 0; k < DD; k++) ip += svl[k] * Gl[k * 97 + tid];
        ip *= (1.0f / 12.0f);
        ipl[tid] = ip;
        ws[OFF_IP + b * FD + tid] = ip;
    }

    // ---- 32-block fan-in (epoch counter: no reset needed across graph replays) ----
    __syncthreads();                               // all ws stores issued & drained
    if (tid == 0) {
        __threadfence();                           // release: L2 writeback (device scope)
        unsigned old = atomicAdd(&g_cnt, 1u);
        unsigned target = (old / (unsigned)BB + 1u) * (unsigned)BB;
        while (atomicAdd(&g_cnt, 0u) < target) { __builtin_amdgcn_s_sleep(8); }
        __threadfence();                           // acquire: invalidate before reads
    }
    __syncthreads();

    // ---- BN stats (redundant per block; 96 threads, 32-iter double loop) ----
    if (tid < FD) {
        const float* ipb = ws + OFF_IP;  const float* A0b = ws + OFF_A0;
        const float* A0sb = ws + OFF_A0S; const float* lib = ws + OFF_LI;
        const int f = tid;
        double Sm = 0, Se2 = 0, Sl = 0;
#pragma unroll 4
        for (int bb2 = 0; bb2 < BB; bb2++) {
            double ip = ipb[bb2 * FD + f], a0 = A0b[bb2], a0s = A0sb[bb2], l = lib[bb2];
            Sm += ip * a0;
            Se2 += ip * ip * a0s + 2.0 * ip * l * a0 + (double)DD * l * l;
            Sl += l;
        }
        double mean = Sm / ((double)BB * DD) + Sl / (double)BB;
        double var = Se2 / ((double)BB * DD) - mean * mean;
        double rstd = 1.0 / sqrt(var + 1e-5);
        float A = (float)rstd * gamma[f];
        bnA_sh[f] = A;
        bnB_sh[f] = beta[f] - (float)mean * A;
    }
    __syncthreads();

    // ---- write out[b] : [FD,D] slab, coalesced float4 along d ----
    float li = li_sh;
    float* ob = out + (size_t)b * FD * DD;
#pragma unroll
    for (int j = 0; j < 12; j++) {
        int e = j * 256 + tid;                     // float4 index 0..3071
        int f = e >> 5;                            // 32 float4 per f-row
        int k4 = (e & 31) * 4;
        float A = bnA_sh[f], Bc = bnB_sh[f], ip = ipl[f];
        float4 o;
        o.x = (att0_sh[k4 + 0] * ip + li) * A + Bc;
        o.y = (att0_sh[k4 + 1] * ip + li) * A + Bc;
        o.z = (att0_sh[k4 + 2] * ip + li) * A + Bc;
        o.w = (att0_sh[k4 + 3] * ip + li) * A + Bc;
        *reinterpret_cast<float4*>(ob + f * DD + k4) = o;
    }
}

extern "C" void kernel_launch(void* const* d_in, const int* in_sizes, int n_in,
                              void* d_out, int out_size, void* d_ws, size_t ws_size,
                              hipStream_t stream) {
    const float* q     = (const float*)d_in[0];
    const float* v     = (const float*)d_in[1];
    const float* hmat  = (const float*)d_in[2];
    const float* hbias = (const float*)d_in[3];
    const float* gamma = (const float*)d_in[4];
    const float* beta  = (const float*)d_in[5];
    float* out = (float*)d_out;
    float* ws = (float*)d_ws;

    k_pass1<<<2560, 256, 0, stream>>>(q, v, ws);
    k_finout<<<BB, 256, 0, stream>>>(v, hmat, hbias, gamma, beta, ws, out);
}

// Round 4
// 122.562 us; speedup vs baseline: 1.0068x; 1.0068x over previous
//
#include <hip/hip_runtime.h>
#include <math.h>

#define BB 32
#define SV 4096
#define SQ 1152
#define DD 128
#define FD 96
#define NS 32                      // chunks over SV
#define RPC (SV / NS)              // 128 rows per chunk
#define LOG2E 1.44269504088896340f

// ---- workspace layout (float offsets) ----
// G: [B,D,FD] group-of-12 sums of q        393216 floats
// P: [B,NS,6,D] partial v moments M1..M6   786432 floats
// att0:[B,D]  li/A0/A0s:[B]  ip:[B,FD]
#define OFF_G    0
#define OFF_P    393216
#define OFF_ATT0 1179648
#define OFF_LI   1183744
#define OFF_A0   1183776
#define OFF_A0S  1183808
#define OFF_IP   1183840

// K1 (fused): blocks [0,1024): v -> moment partials; blocks [1024,2560): q -> G.
__global__ __launch_bounds__(256) void k_pass1(const float* __restrict__ q,
                                               const float* __restrict__ v,
                                               float* __restrict__ ws) {
    __shared__ float red[6][8][DD];   // 24 KB (v-branch only)
    if (blockIdx.x < 1024) {
        int b = blockIdx.x >> 5, chunk = blockIdx.x & 31;
        int lane = threadIdx.x & 31, rowg = threadIdx.x >> 5;   // 8 rows in flight
        int d0 = lane * 4;
        const float* base = v + ((size_t)b * SV + (size_t)chunk * RPC) * DD;
        float s1[4] = {}, s2[4] = {}, s3[4] = {}, s4[4] = {}, s5[4] = {}, s6[4] = {};
        for (int i = 0; i < RPC / 8; i++) {
            float4 x = *reinterpret_cast<const float4*>(base + (size_t)(rowg + 8 * i) * DD + d0);
            float vv[4] = {x.x, x.y, x.z, x.w};
#pragma unroll
            for (int j = 0; j < 4; j++) {
                float a = vv[j], a2 = a * a, a4 = a2 * a2;
                s1[j] += a;       s2[j] += a2;      s3[j] += a2 * a;
                s4[j] += a4;      s5[j] += a4 * a;  s6[j] += a4 * a2;
            }
        }
#pragma unroll
        for (int j = 0; j < 4; j++) {
            red[0][rowg][d0 + j] = s1[j]; red[1][rowg][d0 + j] = s2[j];
            red[2][rowg][d0 + j] = s3[j]; red[3][rowg][d0 + j] = s4[j];
            red[4][rowg][d0 + j] = s5[j]; red[5][rowg][d0 + j] = s6[j];
        }
        __syncthreads();
        for (int t = threadIdx.x; t < 6 * DD; t += 256) {
            int m = t >> 7, d = t & (DD - 1);
            float a = 0;
#pragma unroll
            for (int r = 0; r < 8; r++) a += red[m][r][d];
            ws[OFF_P + ((size_t)(b * NS + chunk) * 6 + m) * DD + d] = a;
        }
    } else {
        int g = (blockIdx.x - 1024) * 256 + threadIdx.x;   // 0..393215
        const float4* p = reinterpret_cast<const float4*>(q + (size_t)g * 12);
        float4 a = p[0], b4 = p[1], c = p[2];
        ws[OFF_G + g] = ((a.x + a.y) + (a.z + a.w)) + ((b4.x + b4.y) + (b4.z + b4.w))
                      + ((c.x + c.y) + (c.z + c.w));
    }
}

// K2: per-batch finalize. One block per b, 256 threads. No LDS staging of G:
// all G/P consumers read L2 directly; moments (tid<128) and qs (tid>=128)
// overlap in phase 1. v0..v2 loads hoisted to hide the cold-HBM miss.
__global__ __launch_bounds__(256) void k_finalize(const float* __restrict__ v,
                                                  const float* __restrict__ hmat,
                                                  const float* __restrict__ hbias,
                                                  float* __restrict__ ws) {
    int b = blockIdx.x, tid = threadIdx.x;
    __shared__ float qsl[DD], svl[DD];
    __shared__ float hm_l[3], hb_l[3];
    __shared__ float redc[10];
    __shared__ float sumq_sh;
    const float* Gb = ws + OFF_G + (size_t)b * DD * FD;
    float M1 = 0, M2 = 0, M3 = 0, M4 = 0, M5 = 0, M6 = 0;
    float v0 = 0, v1 = 0, v2 = 0;
    if (tid < 128) {                               // moments reduction (coalesced over d)
        v0 = v[((size_t)b * SV + 0) * DD + tid];   // hoisted: cold-HBM miss hides here
        v1 = v[((size_t)b * SV + 1) * DD + tid];
        v2 = v[((size_t)b * SV + 2) * DD + tid];
        const float* P = ws + OFF_P;
#pragma unroll 4
        for (int ch = 0; ch < NS; ch++) {
            const float* p = P + (size_t)(b * NS + ch) * 6 * DD + tid;
            M1 += p[0];      M2 += p[DD];     M3 += p[2 * DD];
            M4 += p[3 * DD]; M5 += p[4 * DD]; M6 += p[5 * DD];
        }
        svl[tid] = M1;
    } else {
        if (tid < 131) {                           // hm/hb (4-way ILP accumulators)
            int c = tid - 128;
            float h0 = 0, h1 = 0, h2 = 0, h3 = 0;
            for (int x2 = 0; x2 < FD; x2 += 4) {
                h0 += hmat[c * FD + x2];     h1 += hmat[c * FD + x2 + 1];
                h2 += hmat[c * FD + x2 + 2]; h3 += hmat[c * FD + x2 + 3];
            }
            hm_l[c] = (h0 + h1) + (h2 + h3); hb_l[c] = hbias[c];
        }
        int d = tid - 128;                         // qs row sums straight from L2-resident G
        float qs = 0;
#pragma unroll
        for (int t4 = 0; t4 < FD / 4; t4++) {
            float4 x = *reinterpret_cast<const float4*>(Gb + d * FD + t4 * 4);
            qs += (x.x + x.y) + (x.z + x.w);
        }
        qsl[d] = qs;
    }
    __syncthreads();
    if (tid < 64) {                                // sumq: single-wave shuffle reduce
        float x = qsl[tid] + qsl[tid + 64];
#pragma unroll
        for (int ofs = 32; ofs; ofs >>= 1) x += __shfl_xor(x, ofs, 64);
        if (tid == 0) sumq_sh = x;
    }
    __syncthreads();
    if (tid < 128) {
        float sumq = sumq_sh;
        float att0 = 0, att1 = 0, att2 = 0;
#pragma unroll
        for (int c = 0; c < 3; c++) {
            float alpha = hm_l[c] * sumq, hb = hb_l[c];
            float n2 = alpha * alpha * M2 + 2.f * alpha * hb * M1 + (float)SV * hb * hb;
            float tt = alpha / sqrtf(n2);          // |tt*v| <= ~0.1 -> Taylor-safe
            float Z = (float)SV + tt * (M1 + tt * (0.5f * M2 + tt * ((1.f / 6.f) * M3
                    + tt * ((1.f / 24.f) * M4 + tt * ((1.f / 120.f) * M5
                    + tt * (1.f / 720.f) * M6)))));
            float rz = 1.f / Z, tl = tt * LOG2E;
            att0 += exp2f(v0 * tl) * rz;
            att1 += exp2f(v1 * tl) * rz;
            att2 += exp2f(v2 * tl) * rz;
        }
        ws[OFF_ATT0 + b * DD + tid] = att0;
        float qsv = qsl[tid];
        float vals[5] = {att0, att0 * att0, att1 * qsv, att2 * qsv, M1};
#pragma unroll
        for (int i = 0; i < 5; i++) {
            float x = vals[i];
#pragma unroll
            for (int ofs = 32; ofs; ofs >>= 1) x += __shfl_xor(x, ofs, 64);
            if ((tid & 63) == 0) redc[(tid >> 6) * 5 + i] = x;
        }
    }
    __syncthreads();
    if (tid == 0) {
        float a0 = redc[0] + redc[5], a0s = redc[1] + redc[6];
        float r1 = redc[2] + redc[7], r2 = redc[3] + redc[8], vs = redc[4] + redc[9];
        ws[OFF_A0 + b] = a0; ws[OFF_A0S + b] = a0s;
        ws[OFF_LI + b] = vs * (r1 + r2);           // l1 + l2
    }
    if (tid < FD) {                                // ip GEMV: f-threads read G coalesced (L2)
        float ip = 0;
#pragma unroll 8
        for (int k = 0; k < DD; k++) ip += svl[k] * Gb[k * FD + tid];
        ws[OFF_IP + b * FD + tid] = ip * (1.0f / 12.0f);
    }
}

// K3: output [B,FD,D] with BatchNorm coefficients recomputed per block.
// Each block covers exactly 2 (b,f) pairs (256 threads / 128 k). Threads 0-63
// recompute the closed-form BN stats for those 2 f's (32 lanes per f, double,
// shuffle-reduced). Inputs are ~13 KB, L2-resident after k_finalize; visibility
// is guaranteed by the kernel-launch boundary — no device fences needed.
__global__ __launch_bounds__(256) void k_out(const float* __restrict__ gamma,
                                             const float* __restrict__ beta,
                                             const float* __restrict__ ws,
                                             float* __restrict__ out) {
    __shared__ float bnA_sh[2], bnB_sh[2];
    const float* att0b = ws + OFF_ATT0; const float* ipb = ws + OFF_IP;
    const float* lib = ws + OFF_LI;
    const float* A0b = ws + OFF_A0; const float* A0sb = ws + OFF_A0S;
    int tid = threadIdx.x;
    int bf0 = blockIdx.x * 2;                      // first (b,f) pair of this block
    if (tid < 64) {
        int pair = tid >> 5;                       // 0 or 1
        int f = (bf0 + pair) % FD;
        int bb2 = tid & 31;
        double ip = ipb[bb2 * FD + f], a0 = A0b[bb2], a0s = A0sb[bb2], l = lib[bb2];
        double Sm = ip * a0;
        double Se2 = ip * ip * a0s + 2.0 * ip * l * a0 + (double)DD * l * l;
        double Sl = l;
#pragma unroll
        for (int ofs = 16; ofs; ofs >>= 1) {       // reduce over b within 32-lane group
            Sm  += __shfl_xor(Sm,  ofs, 32);
            Se2 += __shfl_xor(Se2, ofs, 32);
            Sl  += __shfl_xor(Sl,  ofs, 32);
        }
        if ((tid & 31) == 0) {
            double mean = Sm / ((double)BB * DD) + Sl / (double)BB;
            double var = Se2 / ((double)BB * DD) - mean * mean;
            double rstd = 1.0 / sqrt(var + 1e-5);
            float A = (float)rstd * gamma[f];
            bnA_sh[pair] = A;
            bnB_sh[pair] = beta[f] - (float)mean * A;
        }
    }
    __syncthreads();
    int idx = blockIdx.x * 256 + tid;              // 0..393215
    int k = idx & (DD - 1);
    int pair = tid >> 7;
    int bf = bf0 + pair;
    int f = bf % FD;
    int b = bf / FD;
    out[idx] = (att0b[b * DD + k] * ipb[b * FD + f] + lib[b]) * bnA_sh[pair] + bnB_sh[pair];
}

extern "C" void kernel_launch(void* const* d_in, const int* in_sizes, int n_in,
                              void* d_out, int out_size, void* d_ws, size_t ws_size,
                              hipStream_t stream) {
    const float* q     = (const float*)d_in[0];
    const float* v     = (const float*)d_in[1];
    const float* hmat  = (const float*)d_in[2];
    const float* hbias = (const float*)d_in[3];
    const float* gamma = (const float*)d_in[4];
    const float* beta  = (const float*)d_in[5];
    float* out = (float*)d_out;
    float* ws = (float*)d_ws;

    k_pass1<<<2560, 256, 0, stream>>>(q, v, ws);
    k_finalize<<<BB, 256, 0, stream>>>(v, hmat, hbias, ws);
    k_out<<<(BB * FD * DD) / 256, 256, 0, stream>>>(gamma, beta, ws, out);
}

// Round 5
// 120.833 us; speedup vs baseline: 1.0212x; 1.0143x over previous
//
#include <hip/hip_runtime.h>
#include <math.h>

#define BB 32
#define SV 4096
#define SQ 1152
#define DD 128
#define FD 96
#define NS 32                      // chunks over SV
#define RPC (SV / NS)              // 128 rows per chunk
#define LOG2E 1.44269504088896340f

// ---- workspace layout (float offsets) ----
// G: [B,D,FD] group-of-12 sums of q        393216 floats
// P: [B,NS,6,D] partial v moments M1..M6   786432 floats
// att0:[B,D]  li/A0/A0s:[B]  ip:[B,FD]
#define OFF_G    0
#define OFF_P    393216
#define OFF_ATT0 1179648
#define OFF_LI   1183744
#define OFF_A0   1183776
#define OFF_A0S  1183808
#define OFF_IP   1183840

// K1 (fused): blocks [0,1024): v -> moment partials; blocks [1024,2560): q -> G.
__global__ __launch_bounds__(256) void k_pass1(const float* __restrict__ q,
                                               const float* __restrict__ v,
                                               float* __restrict__ ws) {
    __shared__ float red[6][8][DD];   // 24 KB (v-branch only)
    if (blockIdx.x < 1024) {
        int b = blockIdx.x >> 5, chunk = blockIdx.x & 31;
        int lane = threadIdx.x & 31, rowg = threadIdx.x >> 5;   // 8 rows in flight
        int d0 = lane * 4;
        const float* base = v + ((size_t)b * SV + (size_t)chunk * RPC) * DD;
        float s1[4] = {}, s2[4] = {}, s3[4] = {}, s4[4] = {}, s5[4] = {}, s6[4] = {};
        for (int i = 0; i < RPC / 8; i++) {
            float4 x = *reinterpret_cast<const float4*>(base + (size_t)(rowg + 8 * i) * DD + d0);
            float vv[4] = {x.x, x.y, x.z, x.w};
#pragma unroll
            for (int j = 0; j < 4; j++) {
                float a = vv[j], a2 = a * a, a4 = a2 * a2;
                s1[j] += a;       s2[j] += a2;      s3[j] += a2 * a;
                s4[j] += a4;      s5[j] += a4 * a;  s6[j] += a4 * a2;
            }
        }
#pragma unroll
        for (int j = 0; j < 4; j++) {
            red[0][rowg][d0 + j] = s1[j]; red[1][rowg][d0 + j] = s2[j];
            red[2][rowg][d0 + j] = s3[j]; red[3][rowg][d0 + j] = s4[j];
            red[4][rowg][d0 + j] = s5[j]; red[5][rowg][d0 + j] = s6[j];
        }
        __syncthreads();
        for (int t = threadIdx.x; t < 6 * DD; t += 256) {
            int m = t >> 7, d = t & (DD - 1);
            float a = 0;
#pragma unroll
            for (int r = 0; r < 8; r++) a += red[m][r][d];
            ws[OFF_P + ((size_t)(b * NS + chunk) * 6 + m) * DD + d] = a;
        }
    } else {
        int g = (blockIdx.x - 1024) * 256 + threadIdx.x;   // 0..393215
        const float4* p = reinterpret_cast<const float4*>(q + (size_t)g * 12);
        float4 a = p[0], b4 = p[1], c = p[2];
        ws[OFF_G + g] = ((a.x + a.y) + (a.z + a.w)) + ((b4.x + b4.y) + (b4.z + b4.w))
                      + ((c.x + c.y) + (c.z + c.w));
    }
}

// K2: per-batch finalize. One block per b, 256 threads. (Round-2 structure —
// LDS-staged G with +1-padded stride — empirically fastest; r4's L2-direct
// variant was +1.7 us.) v0..v2 loads hoisted so the cold-HBM miss hides
// under the G-staging / moments phase.
__global__ __launch_bounds__(256) void k_finalize(const float* __restrict__ v,
                                                  const float* __restrict__ hmat,
                                                  const float* __restrict__ hbias,
                                                  float* __restrict__ ws) {
    int b = blockIdx.x, tid = threadIdx.x;
    __shared__ float Gl[DD * 97];                 // padded: stride 96 would 32-way conflict
    __shared__ float qsl[DD], svl[DD];
    __shared__ float hm_l[3], hb_l[3];
    __shared__ float redc[10];
    __shared__ float sumq_sh;
    const float* Gb = ws + OFF_G + (size_t)b * DD * FD;
    float v0 = 0, v1 = 0, v2 = 0;
    if (tid < 128) {                              // hoisted: ~900cy cold miss overlaps staging
        v0 = v[((size_t)b * SV + 0) * DD + tid];
        v1 = v[((size_t)b * SV + 1) * DD + tid];
        v2 = v[((size_t)b * SV + 2) * DD + tid];
    }
#pragma unroll
    for (int i = 0; i < 12; i++) {                // stage G[b] (12288 floats) coalesced
        int idx = (i * 256 + tid) * 4;
        float4 x = *reinterpret_cast<const float4*>(Gb + idx);
        float xv[4] = {x.x, x.y, x.z, x.w};
#pragma unroll
        for (int j = 0; j < 4; j++) {
            int e = idx + j, dd = e / 96, f = e - dd * 96;
            Gl[dd * 97 + f] = xv[j];
        }
    }
    if (tid >= 128 && tid < 131) {
        int c = tid - 128;
        float h0 = 0, h1 = 0, h2 = 0, h3 = 0;
        for (int x2 = 0; x2 < FD; x2 += 4) {
            h0 += hmat[c * FD + x2];     h1 += hmat[c * FD + x2 + 1];
            h2 += hmat[c * FD + x2 + 2]; h3 += hmat[c * FD + x2 + 3];
        }
        hm_l[c] = (h0 + h1) + (h2 + h3); hb_l[c] = hbias[c];
    }
    __syncthreads();
    float M1 = 0, M2 = 0, M3 = 0, M4 = 0, M5 = 0, M6 = 0;
    if (tid < 128) {                               // moments reduction (coalesced over d)
        const float* P = ws + OFF_P;
#pragma unroll 4
        for (int ch = 0; ch < NS; ch++) {
            const float* p = P + (size_t)(b * NS + ch) * 6 * DD + tid;
            M1 += p[0];      M2 += p[DD];     M3 += p[2 * DD];
            M4 += p[3 * DD]; M5 += p[4 * DD]; M6 += p[5 * DD];
        }
        svl[tid] = M1;
    } else {
        int d = tid - 128;                         // qs row sums from LDS (conflict-free)
        float qs = 0;
#pragma unroll 8
        for (int f = 0; f < FD; f++) qs += Gl[d * 97 + f];
        qsl[d] = qs;
    }
    __syncthreads();
    if (tid < 64) {                                // sumq: single-wave shuffle reduce
        float x = qsl[tid] + qsl[tid + 64];
#pragma unroll
        for (int ofs = 32; ofs; ofs >>= 1) x += __shfl_xor(x, ofs, 64);
        if (tid == 0) sumq_sh = x;
    }
    __syncthreads();
    if (tid < 128) {
        float sumq = sumq_sh;
        float att0 = 0, att1 = 0, att2 = 0;
#pragma unroll
        for (int c = 0; c < 3; c++) {
            float alpha = hm_l[c] * sumq, hb = hb_l[c];
            float n2 = alpha * alpha * M2 + 2.f * alpha * hb * M1 + (float)SV * hb * hb;
            float tt = alpha / sqrtf(n2);          // |tt*v| <= ~0.1 -> Taylor-safe
            float Z = (float)SV + tt * (M1 + tt * (0.5f * M2 + tt * ((1.f / 6.f) * M3
                    + tt * ((1.f / 24.f) * M4 + tt * ((1.f / 120.f) * M5
                    + tt * (1.f / 720.f) * M6)))));
            float rz = 1.f / Z, tl = tt * LOG2E;
            att0 += exp2f(v0 * tl) * rz;
            att1 += exp2f(v1 * tl) * rz;
            att2 += exp2f(v2 * tl) * rz;
        }
        ws[OFF_ATT0 + b * DD + tid] = att0;
        float qsv = qsl[tid];
        float vals[5] = {att0, att0 * att0, att1 * qsv, att2 * qsv, M1};
#pragma unroll
        for (int i = 0; i < 5; i++) {
            float x = vals[i];
#pragma unroll
            for (int ofs = 32; ofs; ofs >>= 1) x += __shfl_xor(x, ofs, 64);
            if ((tid & 63) == 0) redc[(tid >> 6) * 5 + i] = x;
        }
    }
    __syncthreads();
    if (tid == 0) {
        float a0 = redc[0] + redc[5], a0s = redc[1] + redc[6];
        float r1 = redc[2] + redc[7], r2 = redc[3] + redc[8], vs = redc[4] + redc[9];
        ws[OFF_A0 + b] = a0; ws[OFF_A0S + b] = a0s;
        ws[OFF_LI + b] = vs * (r1 + r2);           // l1 + l2
    }
    if (tid < FD) {                                // ip[b,f] GEMV from LDS
        float ip = 0;
#pragma unroll 8
        for (int k = 0; k < DD; k++) ip += svl[k] * Gl[k * 97 + tid];
        ws[OFF_IP + b * FD + tid] = ip * (1.0f / 12.0f);
    }
}

// K3: output [B,FD,D] with BatchNorm coefficients recomputed per block.
// Each block covers exactly 2 (b,f) pairs (256 threads / 128 k). Threads 0-63
// recompute the closed-form BN stats for those 2 f's (32 lanes per f, double,
// shuffle-reduced). Inputs are ~13 KB, L2-resident after k_finalize; visibility
// is guaranteed by the kernel-launch boundary — no device fences needed.
__global__ __launch_bounds__(256) void k_out(const float* __restrict__ gamma,
                                             const float* __restrict__ beta,
                                             const float* __restrict__ ws,
                                             float* __restrict__ out) {
    __shared__ float bnA_sh[2], bnB_sh[2];
    const float* att0b = ws + OFF_ATT0; const float* ipb = ws + OFF_IP;
    const float* lib = ws + OFF_LI;
    const float* A0b = ws + OFF_A0; const float* A0sb = ws + OFF_A0S;
    int tid = threadIdx.x;
    int bf0 = blockIdx.x * 2;                      // first (b,f) pair of this block
    if (tid < 64) {
        int pair = tid >> 5;                       // 0 or 1
        int f = (bf0 + pair) % FD;
        int bb2 = tid & 31;
        double ip = ipb[bb2 * FD + f], a0 = A0b[bb2], a0s = A0sb[bb2], l = lib[bb2];
        double Sm = ip * a0;
        double Se2 = ip * ip * a0s + 2.0 * ip * l * a0 + (double)DD * l * l;
        double Sl = l;
#pragma unroll
        for (int ofs = 16; ofs; ofs >>= 1) {       // reduce over b within 32-lane group
            Sm  += __shfl_xor(Sm,  ofs, 32);
            Se2 += __shfl_xor(Se2, ofs, 32);
            Sl  += __shfl_xor(Sl,  ofs, 32);
        }
        if ((tid & 31) == 0) {
            double mean = Sm / ((double)BB * DD) + Sl / (double)BB;
            double var = Se2 / ((double)BB * DD) - mean * mean;
            double rstd = 1.0 / sqrt(var + 1e-5);
            float A = (float)rstd * gamma[f];
            bnA_sh[pair] = A;
            bnB_sh[pair] = beta[f] - (float)mean * A;
        }
    }
    __syncthreads();
    int idx = blockIdx.x * 256 + tid;              // 0..393215
    int k = idx & (DD - 1);
    int pair = tid >> 7;
    int bf = bf0 + pair;
    int f = bf % FD;
    int b = bf / FD;
    out[idx] = (att0b[b * DD + k] * ipb[b * FD + f] + lib[b]) * bnA_sh[pair] + bnB_sh[pair];
}

extern "C" void kernel_launch(void* const* d_in, const int* in_sizes, int n_in,
                              void* d_out, int out_size, void* d_ws, size_t ws_size,
                              hipStream_t stream) {
    const float* q     = (const float*)d_in[0];
    const float* v     = (const float*)d_in[1];
    const float* hmat  = (const float*)d_in[2];
    const float* hbias = (const float*)d_in[3];
    const float* gamma = (const float*)d_in[4];
    const float* beta  = (const float*)d_in[5];
    float* out = (float*)d_out;
    float* ws = (float*)d_ws;

    k_pass1<<<2560, 256, 0, stream>>>(q, v, ws);
    k_finalize<<<BB, 256, 0, stream>>>(v, hmat, hbias, ws);
    k_out<<<(BB * FD * DD) / 256, 256, 0, stream>>>(gamma, beta, ws, out);
}